// Round 1
// baseline (4261.859 us; speedup 1.0000x reference)
//
#include <hip/hip_runtime.h>
#include <hip/hip_bf16.h>
#include <math.h>

// GCN stack: 3x [GCNConv + ReLU] + MLP head (64->32 relu ->40) + log_softmax.
// Aggregation factored: out[d] = dinv[d] * (sum_{edges s->d} h'[s] + h'[d]),
// h' = dinv * (x @ W).  Self-loop term seeds the accumulator in the GEMM.

#define DIMF 64

__global__ __launch_bounds__(256) void deg_init(float* deg, int n) {
    int i = blockIdx.x * 256 + threadIdx.x;
    if (i < n) deg[i] = 1.0f;               // self loop
}

__global__ __launch_bounds__(256) void deg_count(const int* __restrict__ dst,
                                                 float* __restrict__ deg, int E) {
    int e = blockIdx.x * 256 + threadIdx.x;
    if (e < E) atomicAdd(&deg[dst[e]], 1.0f);
}

__global__ __launch_bounds__(256) void deg_inv(float* deg, int n) {
    int i = blockIdx.x * 256 + threadIdx.x;
    if (i < n) deg[i] = 1.0f / sqrtf(deg[i]);   // deg >= 1 always (self loop)
}

// hprime = dinv[row] * (xin @ W);  acc seeded with hprime (self-loop term).
// Block: 256 threads, 32 rows x 64 cols per block.
__global__ __launch_bounds__(256) void gemm_scale(
    const float* __restrict__ xin, const float* __restrict__ W,
    const float* __restrict__ dinv, float* __restrict__ hprime,
    float* __restrict__ acc, int n)
{
    __shared__ float Ws[64 * 64];        // 16 KB
    __shared__ float Xs[32][65];         // 8.3 KB, +1 pad
    int t = threadIdx.x;
    for (int i = t; i < 64 * 64; i += 256) Ws[i] = W[i];
    int row0 = blockIdx.x * 32;
    for (int i = t; i < 32 * 64; i += 256) {
        int r = i >> 6, c = i & 63;
        int gr = row0 + r;
        Xs[r][c] = (gr < n) ? xin[(size_t)gr * DIMF + c] : 0.0f;
    }
    __syncthreads();
    int col = t & 63;
    int rbase = (t >> 6) * 8;            // 0,8,16,24
    float av[8];
#pragma unroll
    for (int rr = 0; rr < 8; rr++) av[rr] = 0.0f;
    for (int k = 0; k < 64; k++) {
        float w = Ws[k * 64 + col];      // consecutive lanes -> consecutive banks
#pragma unroll
        for (int rr = 0; rr < 8; rr++)   // Xs read is wave-broadcast (same addr)
            av[rr] = fmaf(Xs[rbase + rr][k], w, av[rr]);
    }
#pragma unroll
    for (int rr = 0; rr < 8; rr++) {
        int gr = row0 + rbase + rr;
        if (gr < n) {
            float v = av[rr] * dinv[gr];
            hprime[(size_t)gr * DIMF + col] = v;
            acc[(size_t)gr * DIMF + col]   = v;
        }
    }
}

// One thread per (edge, 4 features): float4 gather + 4 f32 atomics.
__global__ __launch_bounds__(256) void scatter_edges(
    const int* __restrict__ src, const int* __restrict__ dst,
    const float* __restrict__ hprime, float* __restrict__ acc, int E)
{
    long long tid = (long long)blockIdx.x * 256 + threadIdx.x;
    int e = (int)(tid >> 4);
    if (e >= E) return;
    int f4 = (int)(tid & 15) << 2;
    int s = src[e], d = dst[e];
    const float4 v = *(const float4*)(hprime + (size_t)s * DIMF + f4);
    float* ap = acc + (size_t)d * DIMF + f4;
    atomicAdd(ap + 0, v.x);
    atomicAdd(ap + 1, v.y);
    atomicAdd(ap + 2, v.z);
    atomicAdd(ap + 3, v.w);
}

// xout = relu(dinv[node] * acc + b[f])
__global__ __launch_bounds__(256) void finish_relu(
    const float* __restrict__ acc, const float* __restrict__ dinv,
    const float* __restrict__ b, float* __restrict__ xout, int n)
{
    int i = blockIdx.x * 256 + threadIdx.x;
    if (i < n * DIMF) {
        int node = i >> 6, f = i & 63;
        float v = fmaf(dinv[node], acc[i], b[f]);
        xout[i] = v > 0.0f ? v : 0.0f;
    }
}

// MLP head + log_softmax. 128 threads = 128 nodes per block; X tile in LDS.
__global__ __launch_bounds__(128) void head_kernel(
    const float* __restrict__ x, const float* __restrict__ Wp1,
    const float* __restrict__ bp1, const float* __restrict__ Wp2,
    const float* __restrict__ bp2, float* __restrict__ out, int n)
{
    __shared__ float Xs[128][65];        // 33.3 KB
    __shared__ float W1s[64 * 32];       // 8 KB
    __shared__ float W2s[32 * 40];       // 5 KB
    __shared__ float b1s[32], b2s[40];
    int t = threadIdx.x;
    for (int i = t; i < 64 * 32; i += 128) W1s[i] = Wp1[i];
    for (int i = t; i < 32 * 40; i += 128) W2s[i] = Wp2[i];
    if (t < 32) b1s[t] = bp1[t];
    if (t < 40) b2s[t] = bp2[t];
    int row0 = blockIdx.x * 128;
    for (int i = t; i < 128 * 64; i += 128) {
        int r = i >> 6, c = i & 63;
        int gr = row0 + r;
        Xs[r][c] = (gr < n) ? x[(size_t)gr * DIMF + c] : 0.0f;
    }
    __syncthreads();
    int node = row0 + t;
    if (node >= n) return;

    float h[32];
#pragma unroll
    for (int j = 0; j < 32; j++) h[j] = b1s[j];
    for (int k = 0; k < 64; k++) {
        float xv = Xs[t][k];             // stride-65 rows: conflict-free
#pragma unroll
        for (int j = 0; j < 32; j++) h[j] = fmaf(xv, W1s[k * 32 + j], h[j]);
    }
#pragma unroll
    for (int j = 0; j < 32; j++) h[j] = h[j] > 0.0f ? h[j] : 0.0f;

    float o[40];
#pragma unroll
    for (int j = 0; j < 40; j++) o[j] = b2s[j];
    for (int k = 0; k < 32; k++) {
        float hv = h[k];
#pragma unroll
        for (int j = 0; j < 40; j++) o[j] = fmaf(hv, W2s[k * 40 + j], o[j]);
    }
    float m = o[0];
#pragma unroll
    for (int j = 1; j < 40; j++) m = fmaxf(m, o[j]);
    float sum = 0.0f;
#pragma unroll
    for (int j = 0; j < 40; j++) sum += expf(o[j] - m);
    float lse = logf(sum) + m;
    float* op = out + (size_t)node * 40;
#pragma unroll
    for (int j = 0; j < 40; j++) op[j] = o[j] - lse;
}

extern "C" void kernel_launch(void* const* d_in, const int* in_sizes, int n_in,
                              void* d_out, int out_size, void* d_ws, size_t ws_size,
                              hipStream_t stream)
{
    const float* x  = (const float*)d_in[0];
    const int*   ei = (const int*)d_in[1];
    const int E = in_sizes[1] / 2;
    const int n = in_sizes[0] / DIMF;
    const int* src = ei;
    const int* dst = ei + E;
    const float* W[3] = {(const float*)d_in[3], (const float*)d_in[5], (const float*)d_in[7]};
    const float* b[3] = {(const float*)d_in[4], (const float*)d_in[6], (const float*)d_in[8]};
    const float* Wp1 = (const float*)d_in[9];
    const float* bp1 = (const float*)d_in[10];
    const float* Wp2 = (const float*)d_in[11];
    const float* bp2 = (const float*)d_in[12];
    float* out = (float*)d_out;

    // Workspace layout (floats): dinv[n] | hprime[n*64] | acc[n*64] | xbuf[n*64]
    float* dinv   = (float*)d_ws;
    float* hprime = dinv + n;
    float* acc    = hprime + (size_t)n * DIMF;
    float* xbuf   = acc + (size_t)n * DIMF;

    hipLaunchKernelGGL(deg_init,  dim3((n + 255) / 256), dim3(256), 0, stream, dinv, n);
    hipLaunchKernelGGL(deg_count, dim3((E + 255) / 256), dim3(256), 0, stream, dst, dinv, E);
    hipLaunchKernelGGL(deg_inv,   dim3((n + 255) / 256), dim3(256), 0, stream, dinv, n);

    const float* xin = x;
    for (int l = 0; l < 3; l++) {
        hipLaunchKernelGGL(gemm_scale, dim3((n + 31) / 32), dim3(256), 0, stream,
                           xin, W[l], dinv, hprime, acc, n);
        long long sth = (long long)E * 16;
        hipLaunchKernelGGL(scatter_edges, dim3((unsigned)((sth + 255) / 256)), dim3(256), 0,
                           stream, src, dst, hprime, acc, E);
        hipLaunchKernelGGL(finish_relu, dim3((n * DIMF + 255) / 256), dim3(256), 0, stream,
                           acc, dinv, b[l], xbuf, n);
        xin = xbuf;
    }
    hipLaunchKernelGGL(head_kernel, dim3((n + 127) / 128), dim3(128), 0, stream,
                       xbuf, Wp1, bp1, Wp2, bp2, out, n);
}

// Round 2
// 795.238 us; speedup vs baseline: 5.3592x; 5.3592x over previous
//
#include <hip/hip_runtime.h>
#include <hip/hip_bf16.h>
#include <math.h>

// GCN stack: 3x [GCNConv + ReLU] + MLP head (64->32 relu ->40) + log_softmax.
// R2: push-scatter (f32 atomics, 1.29 ms/layer) replaced by CSR build (once)
// + pull-gather per layer (no feature atomics).
// out[d] = relu(dinv[d] * (h'[d] + sum_{s in N_in(d)} h'[s]) + b),
// h' = dinv * (x @ W).

#define DIMF 64

// ---------------- CSR build ----------------

__global__ __launch_bounds__(256) void zero_counts(int* cnt, int n) {
    int i = blockIdx.x * 256 + threadIdx.x;
    if (i < n) cnt[i] = 0;
}

__global__ __launch_bounds__(256) void hist_dst(const int* __restrict__ dst,
                                                int* __restrict__ cnt, int E) {
    int e = blockIdx.x * 256 + threadIdx.x;
    if (e < E) atomicAdd(&cnt[dst[e]], 1);
}

// Per-block exclusive scan of cnt -> row_start (partial), block totals -> bsum.
__global__ __launch_bounds__(256) void scan_block(const int* __restrict__ cnt,
                                                  int* __restrict__ row_start,
                                                  int* __restrict__ bsum, int n) {
    __shared__ int s[256];
    int t = threadIdx.x;
    int i = blockIdx.x * 256 + t;
    int c = (i < n) ? cnt[i] : 0;
    s[t] = c;
    __syncthreads();
    for (int off = 1; off < 256; off <<= 1) {
        int v = (t >= off) ? s[t - off] : 0;
        __syncthreads();
        s[t] += v;
        __syncthreads();
    }
    int incl = s[t];
    if (i < n) row_start[i] = incl - c;
    if (t == 255) bsum[blockIdx.x] = incl;
}

// Single-block exclusive scan of block sums (nb <= 512).
__global__ __launch_bounds__(512) void scan_bsum(int* __restrict__ bsum, int nb) {
    __shared__ int s[512];
    int t = threadIdx.x;
    int c = (t < nb) ? bsum[t] : 0;
    s[t] = c;
    __syncthreads();
    for (int off = 1; off < 512; off <<= 1) {
        int v = (t >= off) ? s[t - off] : 0;
        __syncthreads();
        s[t] += v;
        __syncthreads();
    }
    if (t < nb) bsum[t] = s[t] - c;   // exclusive
}

// row_start += bsum[blk]; cursor (=cnt reused) = row_start; dinv = rsqrt(deg+1).
__global__ __launch_bounds__(256) void scan_finalize(
    int* __restrict__ cnt, int* __restrict__ row_start,
    const int* __restrict__ bsum, float* __restrict__ dinv, int n, int E) {
    int i = blockIdx.x * 256 + threadIdx.x;
    if (i < n) {
        int c = cnt[i];
        int rsf = row_start[i] + bsum[i >> 8];
        row_start[i] = rsf;
        cnt[i] = rsf;                        // becomes the placement cursor
        dinv[i] = rsqrtf((float)c + 1.0f);   // +1 self loop
    }
    if (i == 0) row_start[n] = E;
}

__global__ __launch_bounds__(256) void place_edges(
    const int* __restrict__ src, const int* __restrict__ dst,
    int* __restrict__ cursor, int* __restrict__ csr_src, int E) {
    int e = blockIdx.x * 256 + threadIdx.x;
    if (e < E) {
        int p = atomicAdd(&cursor[dst[e]], 1);
        csr_src[p] = src[e];
    }
}

// ---------------- per-layer kernels ----------------

// hprime = dinv[row] * (xin @ W).  32 rows x 64 cols per 256-thread block.
__global__ __launch_bounds__(256) void gemm_scale(
    const float* __restrict__ xin, const float* __restrict__ W,
    const float* __restrict__ dinv, float* __restrict__ hprime, int n)
{
    __shared__ float Ws[64 * 64];        // 16 KB
    __shared__ float Xs[32][65];         // 8.3 KB, +1 pad
    int t = threadIdx.x;
    for (int i = t; i < 64 * 64; i += 256) Ws[i] = W[i];
    int row0 = blockIdx.x * 32;
    for (int i = t; i < 32 * 64; i += 256) {
        int r = i >> 6, c = i & 63;
        int gr = row0 + r;
        Xs[r][c] = (gr < n) ? xin[(size_t)gr * DIMF + c] : 0.0f;
    }
    __syncthreads();
    int col = t & 63;
    int rbase = (t >> 6) * 8;            // 0,8,16,24
    float av[8];
#pragma unroll
    for (int rr = 0; rr < 8; rr++) av[rr] = 0.0f;
    for (int k = 0; k < 64; k++) {
        float w = Ws[k * 64 + col];      // lanes -> consecutive banks
#pragma unroll
        for (int rr = 0; rr < 8; rr++)   // Xs read is wave-broadcast
            av[rr] = fmaf(Xs[rbase + rr][k], w, av[rr]);
    }
#pragma unroll
    for (int rr = 0; rr < 8; rr++) {
        int gr = row0 + rbase + rr;
        if (gr < n)
            hprime[(size_t)gr * DIMF + col] = av[rr] * dinv[gr];
    }
}

// One wave per node; lane = feature. Gather in-neighbors' hprime rows, add
// self loop, scale by dinv[d], bias, relu.
__global__ __launch_bounds__(256) void gather_relu(
    const float* __restrict__ hprime, const int* __restrict__ row_start,
    const int* __restrict__ csr_src, const float* __restrict__ dinv,
    const float* __restrict__ b, float* __restrict__ xout, int n)
{
    int wave = threadIdx.x >> 6;
    int lane = threadIdx.x & 63;
    int node = blockIdx.x * 4 + wave;
    if (node >= n) return;
    int rs = row_start[node];
    int re = row_start[node + 1];
    float acc = hprime[(size_t)node * DIMF + lane];     // self loop
    for (int j0 = rs; j0 < re; j0 += 64) {
        int cnt = re - j0; if (cnt > 64) cnt = 64;
        int idx = (lane < cnt) ? csr_src[j0 + lane] : 0;
        for (int k = 0; k < cnt; k++) {
            int s = __shfl(idx, k);                      // wave-uniform src id
            acc += hprime[(size_t)s * DIMF + lane];      // coalesced 256B row
        }
    }
    float v = fmaf(dinv[node], acc, b[lane]);
    xout[(size_t)node * DIMF + lane] = v > 0.0f ? v : 0.0f;
}

// MLP head + log_softmax. 128 threads = 128 nodes per block.
__global__ __launch_bounds__(128) void head_kernel(
    const float* __restrict__ x, const float* __restrict__ Wp1,
    const float* __restrict__ bp1, const float* __restrict__ Wp2,
    const float* __restrict__ bp2, float* __restrict__ out, int n)
{
    __shared__ float Xs[128][65];        // 33.3 KB
    __shared__ float W1s[64 * 32];       // 8 KB
    __shared__ float W2s[32 * 40];       // 5 KB
    __shared__ float b1s[32], b2s[40];
    int t = threadIdx.x;
    for (int i = t; i < 64 * 32; i += 128) W1s[i] = Wp1[i];
    for (int i = t; i < 32 * 40; i += 128) W2s[i] = Wp2[i];
    if (t < 32) b1s[t] = bp1[t];
    if (t < 40) b2s[t] = bp2[t];
    int row0 = blockIdx.x * 128;
    for (int i = t; i < 128 * 64; i += 128) {
        int r = i >> 6, c = i & 63;
        int gr = row0 + r;
        Xs[r][c] = (gr < n) ? x[(size_t)gr * DIMF + c] : 0.0f;
    }
    __syncthreads();
    int node = row0 + t;
    if (node >= n) return;

    float h[32];
#pragma unroll
    for (int j = 0; j < 32; j++) h[j] = b1s[j];
    for (int k = 0; k < 64; k++) {
        float xv = Xs[t][k];
#pragma unroll
        for (int j = 0; j < 32; j++) h[j] = fmaf(xv, W1s[k * 32 + j], h[j]);
    }
#pragma unroll
    for (int j = 0; j < 32; j++) h[j] = h[j] > 0.0f ? h[j] : 0.0f;

    float o[40];
#pragma unroll
    for (int j = 0; j < 40; j++) o[j] = b2s[j];
    for (int k = 0; k < 32; k++) {
        float hv = h[k];
#pragma unroll
        for (int j = 0; j < 40; j++) o[j] = fmaf(hv, W2s[k * 40 + j], o[j]);
    }
    float m = o[0];
#pragma unroll
    for (int j = 1; j < 40; j++) m = fmaxf(m, o[j]);
    float sum = 0.0f;
#pragma unroll
    for (int j = 0; j < 40; j++) sum += expf(o[j] - m);
    float lse = logf(sum) + m;
    float* op = out + (size_t)node * 40;
#pragma unroll
    for (int j = 0; j < 40; j++) op[j] = o[j] - lse;
}

extern "C" void kernel_launch(void* const* d_in, const int* in_sizes, int n_in,
                              void* d_out, int out_size, void* d_ws, size_t ws_size,
                              hipStream_t stream)
{
    const float* x  = (const float*)d_in[0];
    const int*   ei = (const int*)d_in[1];
    const int E = in_sizes[1] / 2;
    const int n = in_sizes[0] / DIMF;
    const int* src = ei;
    const int* dst = ei + E;
    const float* W[3] = {(const float*)d_in[3], (const float*)d_in[5], (const float*)d_in[7]};
    const float* b[3] = {(const float*)d_in[4], (const float*)d_in[6], (const float*)d_in[8]};
    const float* Wp1 = (const float*)d_in[9];
    const float* bp1 = (const float*)d_in[10];
    const float* Wp2 = (const float*)d_in[11];
    const float* bp2 = (const float*)d_in[12];
    float* out = (float*)d_out;

    const int nb = (n + 255) / 256;      // <= 512 for n <= 131072

    // Workspace layout: cnt[n] | row_start[n+1] | bsum[512] | csr_src[E] |
    //                   dinv[n] | hprime[n*64] | xbuf[n*64]   (ints then floats)
    char* p = (char*)d_ws;
    int* cnt       = (int*)p;                 p += (size_t)n * 4;
    int* row_start = (int*)p;                 p += (size_t)(n + 1) * 4;
    p = (char*)(((size_t)p + 15) & ~(size_t)15);
    int* bsum      = (int*)p;                 p += 512 * 4;
    int* csr_src   = (int*)p;                 p += (size_t)E * 4;
    p = (char*)(((size_t)p + 15) & ~(size_t)15);
    float* dinv    = (float*)p;               p += (size_t)n * 4;
    float* hprime  = (float*)p;               p += (size_t)n * DIMF * 4;
    float* xbuf    = (float*)p;

    // --- CSR build (index-space atomics only) ---
    hipLaunchKernelGGL(zero_counts,  dim3(nb), dim3(256), 0, stream, cnt, n);
    hipLaunchKernelGGL(hist_dst,     dim3((E + 255) / 256), dim3(256), 0, stream, dst, cnt, E);
    hipLaunchKernelGGL(scan_block,   dim3(nb), dim3(256), 0, stream, cnt, row_start, bsum, n);
    hipLaunchKernelGGL(scan_bsum,    dim3(1), dim3(512), 0, stream, bsum, nb);
    hipLaunchKernelGGL(scan_finalize,dim3(nb), dim3(256), 0, stream, cnt, row_start, bsum, dinv, n, E);
    hipLaunchKernelGGL(place_edges,  dim3((E + 255) / 256), dim3(256), 0, stream,
                       src, dst, cnt, csr_src, E);

    // --- 3 GCN layers ---
    const float* xin = x;
    for (int l = 0; l < 3; l++) {
        hipLaunchKernelGGL(gemm_scale, dim3((n + 31) / 32), dim3(256), 0, stream,
                           xin, W[l], dinv, hprime, n);
        hipLaunchKernelGGL(gather_relu, dim3((n + 3) / 4), dim3(256), 0, stream,
                           hprime, row_start, csr_src, dinv, b[l], xbuf, n);
        xin = xbuf;
    }

    // --- head ---
    hipLaunchKernelGGL(head_kernel, dim3((n + 127) / 128), dim3(128), 0, stream,
                       xbuf, Wp1, bp1, Wp2, bp2, out, n);
}

// Round 3
// 720.350 us; speedup vs baseline: 5.9164x; 1.1040x over previous
//
#include <hip/hip_runtime.h>
#include <hip/hip_bf16.h>
#include <math.h>

// GCN stack: 3x [GCNConv + ReLU] + MLP head (64->32 relu ->40) + log_softmax.
// R3: gather restructured — 4 edges x float4 per wave-iteration (dwordx4 MLP)
// + shfl_xor fold, instead of 1 edge x dword. CSR build unchanged.
// out[d] = relu(dinv[d] * (h'[d] + sum_{s in N_in(d)} h'[s]) + b),
// h' = dinv * (x @ W).

#define DIMF 64

// ---------------- CSR build ----------------

__global__ __launch_bounds__(256) void zero_counts(int* cnt, int n) {
    int i = blockIdx.x * 256 + threadIdx.x;
    if (i < n) cnt[i] = 0;
}

__global__ __launch_bounds__(256) void hist_dst(const int* __restrict__ dst,
                                                int* __restrict__ cnt, int E) {
    int e = blockIdx.x * 256 + threadIdx.x;
    if (e < E) atomicAdd(&cnt[dst[e]], 1);
}

// Per-block exclusive scan of cnt -> row_start (partial), block totals -> bsum.
__global__ __launch_bounds__(256) void scan_block(const int* __restrict__ cnt,
                                                  int* __restrict__ row_start,
                                                  int* __restrict__ bsum, int n) {
    __shared__ int s[256];
    int t = threadIdx.x;
    int i = blockIdx.x * 256 + t;
    int c = (i < n) ? cnt[i] : 0;
    s[t] = c;
    __syncthreads();
    for (int off = 1; off < 256; off <<= 1) {
        int v = (t >= off) ? s[t - off] : 0;
        __syncthreads();
        s[t] += v;
        __syncthreads();
    }
    int incl = s[t];
    if (i < n) row_start[i] = incl - c;
    if (t == 255) bsum[blockIdx.x] = incl;
}

// Single-block exclusive scan of block sums (nb <= 512).
__global__ __launch_bounds__(512) void scan_bsum(int* __restrict__ bsum, int nb) {
    __shared__ int s[512];
    int t = threadIdx.x;
    int c = (t < nb) ? bsum[t] : 0;
    s[t] = c;
    __syncthreads();
    for (int off = 1; off < 512; off <<= 1) {
        int v = (t >= off) ? s[t - off] : 0;
        __syncthreads();
        s[t] += v;
        __syncthreads();
    }
    if (t < nb) bsum[t] = s[t] - c;   // exclusive
}

// row_start += bsum[blk]; cursor (=cnt reused) = row_start; dinv = rsqrt(deg+1).
__global__ __launch_bounds__(256) void scan_finalize(
    int* __restrict__ cnt, int* __restrict__ row_start,
    const int* __restrict__ bsum, float* __restrict__ dinv, int n, int E) {
    int i = blockIdx.x * 256 + threadIdx.x;
    if (i < n) {
        int c = cnt[i];
        int rsf = row_start[i] + bsum[i >> 8];
        row_start[i] = rsf;
        cnt[i] = rsf;                        // becomes the placement cursor
        dinv[i] = rsqrtf((float)c + 1.0f);   // +1 self loop
    }
    if (i == 0) row_start[n] = E;
}

__global__ __launch_bounds__(256) void place_edges(
    const int* __restrict__ src, const int* __restrict__ dst,
    int* __restrict__ cursor, int* __restrict__ csr_src, int E) {
    int e = blockIdx.x * 256 + threadIdx.x;
    if (e < E) {
        int p = atomicAdd(&cursor[dst[e]], 1);
        csr_src[p] = src[e];
    }
}

// ---------------- per-layer kernels ----------------

// hprime = dinv[row] * (xin @ W).  32 rows x 64 cols per 256-thread block.
__global__ __launch_bounds__(256) void gemm_scale(
    const float* __restrict__ xin, const float* __restrict__ W,
    const float* __restrict__ dinv, float* __restrict__ hprime, int n)
{
    __shared__ float Ws[64 * 64];        // 16 KB
    __shared__ float Xs[32][65];         // 8.3 KB, +1 pad
    int t = threadIdx.x;
    for (int i = t; i < 64 * 64; i += 256) Ws[i] = W[i];
    int row0 = blockIdx.x * 32;
    for (int i = t; i < 32 * 64; i += 256) {
        int r = i >> 6, c = i & 63;
        int gr = row0 + r;
        Xs[r][c] = (gr < n) ? xin[(size_t)gr * DIMF + c] : 0.0f;
    }
    __syncthreads();
    int col = t & 63;
    int rbase = (t >> 6) * 8;            // 0,8,16,24
    float av[8];
#pragma unroll
    for (int rr = 0; rr < 8; rr++) av[rr] = 0.0f;
    for (int k = 0; k < 64; k++) {
        float w = Ws[k * 64 + col];      // lanes -> consecutive banks
#pragma unroll
        for (int rr = 0; rr < 8; rr++)   // Xs read is wave-broadcast
            av[rr] = fmaf(Xs[rbase + rr][k], w, av[rr]);
    }
#pragma unroll
    for (int rr = 0; rr < 8; rr++) {
        int gr = row0 + rbase + rr;
        if (gr < n)
            hprime[(size_t)gr * DIMF + col] = av[rr] * dinv[gr];
    }
}

// One wave per node. lane = (edge-slot g=lane>>4, feature-quad f4=(lane&15)*4).
// 4 edges in flight per iteration, dwordx4 loads; shfl_xor(16,32) folds the
// 4 edge-slots; lanes 0..15 write the node's row as float4.
__global__ __launch_bounds__(256) void gather_relu(
    const float* __restrict__ hprime, const int* __restrict__ row_start,
    const int* __restrict__ csr_src, const float* __restrict__ dinv,
    const float* __restrict__ b, float* __restrict__ xout, int n)
{
    int wave = threadIdx.x >> 6;
    int lane = threadIdx.x & 63;
    int node = blockIdx.x * 4 + wave;
    if (node >= n) return;
    int g  = lane >> 4;           // edge slot 0..3
    int f4 = (lane & 15) << 2;    // feature base
    int rs = row_start[node];
    int re = row_start[node + 1];

    float4 acc = make_float4(0.0f, 0.0f, 0.0f, 0.0f);
    if (g == 0)                    // self loop, counted once
        acc = *(const float4*)(hprime + (size_t)node * DIMF + f4);

    for (int j0 = rs; j0 < re; j0 += 64) {
        int cnt = re - j0; if (cnt > 64) cnt = 64;
        int idx = (lane < cnt) ? csr_src[j0 + lane] : 0;
        for (int k = 0; k < cnt; k += 4) {
            int s = __shfl(idx, k + g);
            if (k + g < cnt) {
                const float4 v = *(const float4*)(hprime + (size_t)s * DIMF + f4);
                acc.x += v.x; acc.y += v.y; acc.z += v.z; acc.w += v.w;
            }
        }
    }
    // fold the 4 edge-slots: lanes {l, l^16, l^32, l^48} hold same features
    acc.x += __shfl_xor(acc.x, 16); acc.y += __shfl_xor(acc.y, 16);
    acc.z += __shfl_xor(acc.z, 16); acc.w += __shfl_xor(acc.w, 16);
    acc.x += __shfl_xor(acc.x, 32); acc.y += __shfl_xor(acc.y, 32);
    acc.z += __shfl_xor(acc.z, 32); acc.w += __shfl_xor(acc.w, 32);

    if (g == 0) {
        float dv = dinv[node];
        float4 o;
        o.x = fmaxf(fmaf(dv, acc.x, b[f4 + 0]), 0.0f);
        o.y = fmaxf(fmaf(dv, acc.y, b[f4 + 1]), 0.0f);
        o.z = fmaxf(fmaf(dv, acc.z, b[f4 + 2]), 0.0f);
        o.w = fmaxf(fmaf(dv, acc.w, b[f4 + 3]), 0.0f);
        *(float4*)(xout + (size_t)node * DIMF + f4) = o;
    }
}

// MLP head + log_softmax. 128 threads = 128 nodes per block.
__global__ __launch_bounds__(128) void head_kernel(
    const float* __restrict__ x, const float* __restrict__ Wp1,
    const float* __restrict__ bp1, const float* __restrict__ Wp2,
    const float* __restrict__ bp2, float* __restrict__ out, int n)
{
    __shared__ float Xs[128][65];        // 33.3 KB
    __shared__ float W1s[64 * 32];       // 8 KB
    __shared__ float W2s[32 * 40];       // 5 KB
    __shared__ float b1s[32], b2s[40];
    int t = threadIdx.x;
    for (int i = t; i < 64 * 32; i += 128) W1s[i] = Wp1[i];
    for (int i = t; i < 32 * 40; i += 128) W2s[i] = Wp2[i];
    if (t < 32) b1s[t] = bp1[t];
    if (t < 40) b2s[t] = bp2[t];
    int row0 = blockIdx.x * 128;
    for (int i = t; i < 128 * 64; i += 128) {
        int r = i >> 6, c = i & 63;
        int gr = row0 + r;
        Xs[r][c] = (gr < n) ? x[(size_t)gr * DIMF + c] : 0.0f;
    }
    __syncthreads();
    int node = row0 + t;
    if (node >= n) return;

    float h[32];
#pragma unroll
    for (int j = 0; j < 32; j++) h[j] = b1s[j];
    for (int k = 0; k < 64; k++) {
        float xv = Xs[t][k];
#pragma unroll
        for (int j = 0; j < 32; j++) h[j] = fmaf(xv, W1s[k * 32 + j], h[j]);
    }
#pragma unroll
    for (int j = 0; j < 32; j++) h[j] = h[j] > 0.0f ? h[j] : 0.0f;

    float o[40];
#pragma unroll
    for (int j = 0; j < 40; j++) o[j] = b2s[j];
    for (int k = 0; k < 32; k++) {
        float hv = h[k];
#pragma unroll
        for (int j = 0; j < 40; j++) o[j] = fmaf(hv, W2s[k * 40 + j], o[j]);
    }
    float m = o[0];
#pragma unroll
    for (int j = 1; j < 40; j++) m = fmaxf(m, o[j]);
    float sum = 0.0f;
#pragma unroll
    for (int j = 0; j < 40; j++) sum += expf(o[j] - m);
    float lse = logf(sum) + m;
    float* op = out + (size_t)node * 40;
#pragma unroll
    for (int j = 0; j < 40; j++) op[j] = o[j] - lse;
}

extern "C" void kernel_launch(void* const* d_in, const int* in_sizes, int n_in,
                              void* d_out, int out_size, void* d_ws, size_t ws_size,
                              hipStream_t stream)
{
    const float* x  = (const float*)d_in[0];
    const int*   ei = (const int*)d_in[1];
    const int E = in_sizes[1] / 2;
    const int n = in_sizes[0] / DIMF;
    const int* src = ei;
    const int* dst = ei + E;
    const float* W[3] = {(const float*)d_in[3], (const float*)d_in[5], (const float*)d_in[7]};
    const float* b[3] = {(const float*)d_in[4], (const float*)d_in[6], (const float*)d_in[8]};
    const float* Wp1 = (const float*)d_in[9];
    const float* bp1 = (const float*)d_in[10];
    const float* Wp2 = (const float*)d_in[11];
    const float* bp2 = (const float*)d_in[12];
    float* out = (float*)d_out;

    const int nb = (n + 255) / 256;      // <= 512 for n <= 131072

    // Workspace layout: cnt[n] | row_start[n+1] | bsum[512] | csr_src[E] |
    //                   dinv[n] | hprime[n*64] | xbuf[n*64]
    char* p = (char*)d_ws;
    int* cnt       = (int*)p;                 p += (size_t)n * 4;
    int* row_start = (int*)p;                 p += (size_t)(n + 1) * 4;
    p = (char*)(((size_t)p + 15) & ~(size_t)15);
    int* bsum      = (int*)p;                 p += 512 * 4;
    int* csr_src   = (int*)p;                 p += (size_t)E * 4;
    p = (char*)(((size_t)p + 15) & ~(size_t)15);
    float* dinv    = (float*)p;               p += (size_t)n * 4;
    float* hprime  = (float*)p;               p += (size_t)n * DIMF * 4;
    float* xbuf    = (float*)p;

    // --- CSR build (index-space atomics only) ---
    hipLaunchKernelGGL(zero_counts,  dim3(nb), dim3(256), 0, stream, cnt, n);
    hipLaunchKernelGGL(hist_dst,     dim3((E + 255) / 256), dim3(256), 0, stream, dst, cnt, E);
    hipLaunchKernelGGL(scan_block,   dim3(nb), dim3(256), 0, stream, cnt, row_start, bsum, n);
    hipLaunchKernelGGL(scan_bsum,    dim3(1), dim3(512), 0, stream, bsum, nb);
    hipLaunchKernelGGL(scan_finalize,dim3(nb), dim3(256), 0, stream, cnt, row_start, bsum, dinv, n, E);
    hipLaunchKernelGGL(place_edges,  dim3((E + 255) / 256), dim3(256), 0, stream,
                       src, dst, cnt, csr_src, E);

    // --- 3 GCN layers ---
    const float* xin = x;
    for (int l = 0; l < 3; l++) {
        hipLaunchKernelGGL(gemm_scale, dim3((n + 31) / 32), dim3(256), 0, stream,
                           xin, W[l], dinv, hprime, n);
        hipLaunchKernelGGL(gather_relu, dim3((n + 3) / 4), dim3(256), 0, stream,
                           hprime, row_start, csr_src, dinv, b[l], xbuf, n);
        xin = xbuf;
    }

    // --- head ---
    hipLaunchKernelGGL(head_kernel, dim3((n + 127) / 128), dim3(128), 0, stream,
                       xbuf, Wp1, bp1, Wp2, bp2, out, n);
}

// Round 4
// 629.595 us; speedup vs baseline: 6.7692x; 1.1441x over previous
//
#include <hip/hip_runtime.h>
#include <hip/hip_bf16.h>
#include <math.h>

// GCN stack: 3x [GCNConv + ReLU] + MLP head (64->32 relu ->40) + log_softmax.
// R4: hprime stored as bf16 (128B rows = 2 cache lines) -> halves the random
// line-granule traffic in the gather (R3 post-mortem: gather is line-fetch
// bound, not issue bound). Accumulation stays f32.
// out[d] = relu(dinv[d] * (h'[d] + sum_{s in N_in(d)} h'[s]) + b),
// h' = dinv * (x @ W).

#define DIMF 64

// ---------------- CSR build ----------------

__global__ __launch_bounds__(256) void zero_counts(int* cnt, int n) {
    int i = blockIdx.x * 256 + threadIdx.x;
    if (i < n) cnt[i] = 0;
}

__global__ __launch_bounds__(256) void hist_dst(const int* __restrict__ dst,
                                                int* __restrict__ cnt, int E) {
    int e = blockIdx.x * 256 + threadIdx.x;
    if (e < E) atomicAdd(&cnt[dst[e]], 1);
}

// Per-block exclusive scan of cnt -> row_start (partial), block totals -> bsum.
__global__ __launch_bounds__(256) void scan_block(const int* __restrict__ cnt,
                                                  int* __restrict__ row_start,
                                                  int* __restrict__ bsum, int n) {
    __shared__ int s[256];
    int t = threadIdx.x;
    int i = blockIdx.x * 256 + t;
    int c = (i < n) ? cnt[i] : 0;
    s[t] = c;
    __syncthreads();
    for (int off = 1; off < 256; off <<= 1) {
        int v = (t >= off) ? s[t - off] : 0;
        __syncthreads();
        s[t] += v;
        __syncthreads();
    }
    int incl = s[t];
    if (i < n) row_start[i] = incl - c;
    if (t == 255) bsum[blockIdx.x] = incl;
}

// Single-block exclusive scan of block sums (nb <= 512).
__global__ __launch_bounds__(512) void scan_bsum(int* __restrict__ bsum, int nb) {
    __shared__ int s[512];
    int t = threadIdx.x;
    int c = (t < nb) ? bsum[t] : 0;
    s[t] = c;
    __syncthreads();
    for (int off = 1; off < 512; off <<= 1) {
        int v = (t >= off) ? s[t - off] : 0;
        __syncthreads();
        s[t] += v;
        __syncthreads();
    }
    if (t < nb) bsum[t] = s[t] - c;   // exclusive
}

// row_start += bsum[blk]; cursor (=cnt reused) = row_start; dinv = rsqrt(deg+1).
__global__ __launch_bounds__(256) void scan_finalize(
    int* __restrict__ cnt, int* __restrict__ row_start,
    const int* __restrict__ bsum, float* __restrict__ dinv, int n, int E) {
    int i = blockIdx.x * 256 + threadIdx.x;
    if (i < n) {
        int c = cnt[i];
        int rsf = row_start[i] + bsum[i >> 8];
        row_start[i] = rsf;
        cnt[i] = rsf;                        // becomes the placement cursor
        dinv[i] = rsqrtf((float)c + 1.0f);   // +1 self loop
    }
    if (i == 0) row_start[n] = E;
}

__global__ __launch_bounds__(256) void place_edges(
    const int* __restrict__ src, const int* __restrict__ dst,
    int* __restrict__ cursor, int* __restrict__ csr_src, int E) {
    int e = blockIdx.x * 256 + threadIdx.x;
    if (e < E) {
        int p = atomicAdd(&cursor[dst[e]], 1);
        csr_src[p] = src[e];
    }
}

// ---------------- per-layer kernels ----------------

// hprime(bf16) = dinv[row] * (xin @ W).  32 rows x 64 cols per block.
__global__ __launch_bounds__(256) void gemm_scale(
    const float* __restrict__ xin, const float* __restrict__ W,
    const float* __restrict__ dinv, __hip_bfloat16* __restrict__ hprime, int n)
{
    __shared__ float Ws[64 * 64];        // 16 KB
    __shared__ float Xs[32][65];         // 8.3 KB, +1 pad
    int t = threadIdx.x;
    for (int i = t; i < 64 * 64; i += 256) Ws[i] = W[i];
    int row0 = blockIdx.x * 32;
    for (int i = t; i < 32 * 64; i += 256) {
        int r = i >> 6, c = i & 63;
        int gr = row0 + r;
        Xs[r][c] = (gr < n) ? xin[(size_t)gr * DIMF + c] : 0.0f;
    }
    __syncthreads();
    int col = t & 63;
    int rbase = (t >> 6) * 8;            // 0,8,16,24
    float av[8];
#pragma unroll
    for (int rr = 0; rr < 8; rr++) av[rr] = 0.0f;
    for (int k = 0; k < 64; k++) {
        float w = Ws[k * 64 + col];      // lanes -> consecutive banks
#pragma unroll
        for (int rr = 0; rr < 8; rr++)   // Xs read is wave-broadcast
            av[rr] = fmaf(Xs[rbase + rr][k], w, av[rr]);
    }
#pragma unroll
    for (int rr = 0; rr < 8; rr++) {
        int gr = row0 + rbase + rr;
        if (gr < n)
            hprime[(size_t)gr * DIMF + col] = __float2bfloat16(av[rr] * dinv[gr]);
    }
}

// One wave per node. lane = (edge-slot g=lane>>3, feature-oct (lane&7)*8).
// 8 edges in flight per iteration, 16B uint4 loads of bf16x8; f32 unpack+acc;
// shfl_xor(8,16,32) folds the 8 edge-slots; lanes 0..7 write the node row.
__global__ __launch_bounds__(256) void gather_relu(
    const unsigned int* __restrict__ hprime,  // bf16x2 packed, 32 uints/row
    const int* __restrict__ row_start, const int* __restrict__ csr_src,
    const float* __restrict__ dinv, const float* __restrict__ b,
    float* __restrict__ xout, int n)
{
    int wave = threadIdx.x >> 6;
    int lane = threadIdx.x & 63;
    int node = blockIdx.x * 4 + wave;
    if (node >= n) return;
    int g    = lane >> 3;          // edge slot 0..7
    int uoff = (lane & 7) << 2;    // uint index within 32-uint row
    int rs = row_start[node];
    int re = row_start[node + 1];

    float acc[8];
#pragma unroll
    for (int i = 0; i < 8; i++) acc[i] = 0.0f;

#define ADDROW(v)                                                          \
    {                                                                      \
        acc[0] += __uint_as_float((v).x << 16);                            \
        acc[1] += __uint_as_float((v).x & 0xffff0000u);                    \
        acc[2] += __uint_as_float((v).y << 16);                            \
        acc[3] += __uint_as_float((v).y & 0xffff0000u);                    \
        acc[4] += __uint_as_float((v).z << 16);                            \
        acc[5] += __uint_as_float((v).z & 0xffff0000u);                    \
        acc[6] += __uint_as_float((v).w << 16);                            \
        acc[7] += __uint_as_float((v).w & 0xffff0000u);                    \
    }

    if (g == 0) {                  // self loop, counted once
        uint4 v = *(const uint4*)(hprime + (size_t)node * 32 + uoff);
        ADDROW(v);
    }
    for (int j0 = rs; j0 < re; j0 += 64) {
        int cnt = re - j0; if (cnt > 64) cnt = 64;
        int idx = (lane < cnt) ? csr_src[j0 + lane] : 0;
        for (int k = 0; k < cnt; k += 8) {
            int s = __shfl(idx, k + g);
            if (k + g < cnt) {
                uint4 v = *(const uint4*)(hprime + (size_t)s * 32 + uoff);
                ADDROW(v);
            }
        }
    }
#undef ADDROW

    // fold the 8 edge-slots (lanes with equal (lane&7) hold same features)
#pragma unroll
    for (int step = 8; step <= 32; step <<= 1)
#pragma unroll
        for (int i = 0; i < 8; i++) acc[i] += __shfl_xor(acc[i], step);

    if (g == 0) {
        int f8 = (lane & 7) << 3;
        float dv = dinv[node];
        float4 o0, o1;
        o0.x = fmaxf(fmaf(dv, acc[0], b[f8 + 0]), 0.0f);
        o0.y = fmaxf(fmaf(dv, acc[1], b[f8 + 1]), 0.0f);
        o0.z = fmaxf(fmaf(dv, acc[2], b[f8 + 2]), 0.0f);
        o0.w = fmaxf(fmaf(dv, acc[3], b[f8 + 3]), 0.0f);
        o1.x = fmaxf(fmaf(dv, acc[4], b[f8 + 4]), 0.0f);
        o1.y = fmaxf(fmaf(dv, acc[5], b[f8 + 5]), 0.0f);
        o1.z = fmaxf(fmaf(dv, acc[6], b[f8 + 6]), 0.0f);
        o1.w = fmaxf(fmaf(dv, acc[7], b[f8 + 7]), 0.0f);
        float* op = xout + (size_t)node * DIMF + f8;
        *(float4*)(op)     = o0;
        *(float4*)(op + 4) = o1;
    }
}

// MLP head + log_softmax. 128 threads = 128 nodes per block.
__global__ __launch_bounds__(128) void head_kernel(
    const float* __restrict__ x, const float* __restrict__ Wp1,
    const float* __restrict__ bp1, const float* __restrict__ Wp2,
    const float* __restrict__ bp2, float* __restrict__ out, int n)
{
    __shared__ float Xs[128][65];        // 33.3 KB
    __shared__ float W1s[64 * 32];       // 8 KB
    __shared__ float W2s[32 * 40];       // 5 KB
    __shared__ float b1s[32], b2s[40];
    int t = threadIdx.x;
    for (int i = t; i < 64 * 32; i += 128) W1s[i] = Wp1[i];
    for (int i = t; i < 32 * 40; i += 128) W2s[i] = Wp2[i];
    if (t < 32) b1s[t] = bp1[t];
    if (t < 40) b2s[t] = bp2[t];
    int row0 = blockIdx.x * 128;
    for (int i = t; i < 128 * 64; i += 128) {
        int r = i >> 6, c = i & 63;
        int gr = row0 + r;
        Xs[r][c] = (gr < n) ? x[(size_t)gr * DIMF + c] : 0.0f;
    }
    __syncthreads();
    int node = row0 + t;
    if (node >= n) return;

    float h[32];
#pragma unroll
    for (int j = 0; j < 32; j++) h[j] = b1s[j];
    for (int k = 0; k < 64; k++) {
        float xv = Xs[t][k];
#pragma unroll
        for (int j = 0; j < 32; j++) h[j] = fmaf(xv, W1s[k * 32 + j], h[j]);
    }
#pragma unroll
    for (int j = 0; j < 32; j++) h[j] = h[j] > 0.0f ? h[j] : 0.0f;

    float o[40];
#pragma unroll
    for (int j = 0; j < 40; j++) o[j] = b2s[j];
    for (int k = 0; k < 32; k++) {
        float hv = h[k];
#pragma unroll
        for (int j = 0; j < 40; j++) o[j] = fmaf(hv, W2s[k * 40 + j], o[j]);
    }
    float m = o[0];
#pragma unroll
    for (int j = 1; j < 40; j++) m = fmaxf(m, o[j]);
    float sum = 0.0f;
#pragma unroll
    for (int j = 0; j < 40; j++) sum += expf(o[j] - m);
    float lse = logf(sum) + m;
    float* op = out + (size_t)node * 40;
#pragma unroll
    for (int j = 0; j < 40; j++) op[j] = o[j] - lse;
}

extern "C" void kernel_launch(void* const* d_in, const int* in_sizes, int n_in,
                              void* d_out, int out_size, void* d_ws, size_t ws_size,
                              hipStream_t stream)
{
    const float* x  = (const float*)d_in[0];
    const int*   ei = (const int*)d_in[1];
    const int E = in_sizes[1] / 2;
    const int n = in_sizes[0] / DIMF;
    const int* src = ei;
    const int* dst = ei + E;
    const float* W[3] = {(const float*)d_in[3], (const float*)d_in[5], (const float*)d_in[7]};
    const float* b[3] = {(const float*)d_in[4], (const float*)d_in[6], (const float*)d_in[8]};
    const float* Wp1 = (const float*)d_in[9];
    const float* bp1 = (const float*)d_in[10];
    const float* Wp2 = (const float*)d_in[11];
    const float* bp2 = (const float*)d_in[12];
    float* out = (float*)d_out;

    const int nb = (n + 255) / 256;      // <= 512 for n <= 131072

    // Workspace layout: cnt[n] | row_start[n+1] | bsum[512] | csr_src[E] |
    //                   dinv[n] | hprime[n*64 bf16] | xbuf[n*64 f32]
    char* p = (char*)d_ws;
    int* cnt       = (int*)p;                 p += (size_t)n * 4;
    int* row_start = (int*)p;                 p += (size_t)(n + 1) * 4;
    p = (char*)(((size_t)p + 15) & ~(size_t)15);
    int* bsum      = (int*)p;                 p += 512 * 4;
    int* csr_src   = (int*)p;                 p += (size_t)E * 4;
    p = (char*)(((size_t)p + 15) & ~(size_t)15);
    float* dinv    = (float*)p;               p += (size_t)n * 4;
    p = (char*)(((size_t)p + 15) & ~(size_t)15);
    __hip_bfloat16* hprime = (__hip_bfloat16*)p;  p += (size_t)n * DIMF * 2;
    p = (char*)(((size_t)p + 15) & ~(size_t)15);
    float* xbuf    = (float*)p;

    // --- CSR build (index-space atomics only) ---
    hipLaunchKernelGGL(zero_counts,  dim3(nb), dim3(256), 0, stream, cnt, n);
    hipLaunchKernelGGL(hist_dst,     dim3((E + 255) / 256), dim3(256), 0, stream, dst, cnt, E);
    hipLaunchKernelGGL(scan_block,   dim3(nb), dim3(256), 0, stream, cnt, row_start, bsum, n);
    hipLaunchKernelGGL(scan_bsum,    dim3(1), dim3(512), 0, stream, bsum, nb);
    hipLaunchKernelGGL(scan_finalize,dim3(nb), dim3(256), 0, stream, cnt, row_start, bsum, dinv, n, E);
    hipLaunchKernelGGL(place_edges,  dim3((E + 255) / 256), dim3(256), 0, stream,
                       src, dst, cnt, csr_src, E);

    // --- 3 GCN layers ---
    const float* xin = x;
    for (int l = 0; l < 3; l++) {
        hipLaunchKernelGGL(gemm_scale, dim3((n + 31) / 32), dim3(256), 0, stream,
                           xin, W[l], dinv, hprime, n);
        hipLaunchKernelGGL(gather_relu, dim3((n + 3) / 4), dim3(256), 0, stream,
                           (const unsigned int*)hprime, row_start, csr_src, dinv,
                           b[l], xbuf, n);
        xin = xbuf;
    }

    // --- head ---
    hipLaunchKernelGGL(head_kernel, dim3((n + 127) / 128), dim3(128), 0, stream,
                       xbuf, Wp1, bp1, Wp2, bp2, out, n);
}